// Round 2
// baseline (189.508 us; speedup 1.0000x reference)
//
#include <hip/hip_runtime.h>

// OverlapLoss_intra: B=64, S=256. Odd-sliced boxes, per-batch last-occurrence
// of each id in [0,128), pair all distinct present ids sharing a parent
// (parent taken at the id's last occurrence), sum IoU (inter / min-area).
//
// Single-block kernel: 1024 threads = 8 batch-slots x 128 id-lanes, 8 loop
// iterations cover B=64. Final result is STORED to d_out (no memset, no
// global atomics) -> exactly one dispatch per call.

#define S_DIM 256
#define HALF 128
#define SLOTS 8
#define NBATCH 64

__global__ __launch_bounds__(1024)
void overlap_loss_kernel(const float* __restrict__ pred_boxes,
                         const int* __restrict__ idv_arr,
                         const int* __restrict__ parent_arr,
                         float* __restrict__ out) {
    const int t    = threadIdx.x;
    const int slot = t >> 7;     // 0..7  : which batch this group handles
    const int g    = t & 127;    // 0..127: candidate id within batch

    __shared__ int   s_last[SLOTS][HALF];
    __shared__ int   s_par [SLOTS][HALF];
    __shared__ float s_x0[SLOTS][HALF], s_y0[SLOTS][HALF];
    __shared__ float s_x1[SLOTS][HALF], s_y1[SLOTS][HALF];

    float sum = 0.0f;

    for (int k = 0; k < NBATCH / SLOTS; ++k) {
        const int b = k * SLOTS + slot;

        // Phase 0: reset
        s_last[slot][g] = -1;
        __syncthreads();

        // Phase 1: last occurrence of each id among odd slots of row b.
        {
            int idv = idv_arr[b * S_DIM + 2 * g + 1];
            if (idv >= 0 && idv < HALF) atomicMax(&s_last[slot][idv], g);
        }
        __syncthreads();

        // Phase 2: per unique id g, load parent + box at last occurrence.
        int lg = s_last[slot][g];
        int p = -1;
        if (lg >= 0) {
            int flat = b * S_DIM + 2 * lg + 1;
            p = parent_arr[flat];
            float4 bx = reinterpret_cast<const float4*>(pred_boxes)[flat];
            float xc = bx.x * 1440.0f;
            float yc = bx.y * 2560.0f;
            float w  = bx.z * 1440.0f;
            float h  = bx.w * 2560.0f;
            s_x0[slot][g] = xc - 0.5f * w;
            s_y0[slot][g] = yc - 0.5f * h;
            s_x1[slot][g] = xc + 0.5f * w;
            s_y1[slot][g] = yc + 0.5f * h;
        }
        s_par[slot][g] = p;
        __syncthreads();

        // Phase 3: pair id g with every id g2 > g sharing the same parent.
        if (p >= 0) {
            const float ax0 = s_x0[slot][g], ay0 = s_y0[slot][g];
            const float ax1 = s_x1[slot][g], ay1 = s_y1[slot][g];
            const float a1 = (ax1 - ax0) * (ay1 - ay0);
            for (int g2 = g + 1; g2 < HALF; ++g2) {
                if (s_par[slot][g2] == p) {
                    float xl = fmaxf(ax0, s_x0[slot][g2]);
                    float yt = fmaxf(ay0, s_y0[slot][g2]);
                    float xr = fminf(ax1, s_x1[slot][g2]);
                    float yb = fminf(ay1, s_y1[slot][g2]);
                    if (xr >= xl && yb >= yt) {
                        float a2 = (s_x1[slot][g2] - s_x0[slot][g2]) *
                                   (s_y1[slot][g2] - s_y0[slot][g2]);
                        sum += (xr - xl) * (yb - yt) / fminf(a1, a2);
                    }
                }
            }
        }
        __syncthreads();   // protect shared arrays before next-iter overwrite
    }

    // Block-wide reduction: 16 waves of 64 lanes.
    for (int off = 32; off > 0; off >>= 1)
        sum += __shfl_down(sum, off, 64);
    __shared__ float wsum[16];
    if ((t & 63) == 0) wsum[t >> 6] = sum;
    __syncthreads();
    if (t < 16) {
        float v = wsum[t];
        for (int off = 8; off > 0; off >>= 1)
            v += __shfl_down(v, off, 64);
        if (t == 0) out[0] = v;
    }
}

extern "C" void kernel_launch(void* const* d_in, const int* in_sizes, int n_in,
                              void* d_out, int out_size, void* d_ws, size_t ws_size,
                              hipStream_t stream) {
    const float* pred_boxes = (const float*)d_in[0];  // [64,256,4] f32
    const int*   id_        = (const int*)d_in[1];    // [64,256] i32
    const int*   parent_id  = (const int*)d_in[2];    // [64,256] i32
    // d_in[3] = type_id, unused by the reference computation.

    overlap_loss_kernel<<<1, 1024, 0, stream>>>(pred_boxes, id_, parent_id,
                                                (float*)d_out);
}

// Round 3
// 18.946 us; speedup vs baseline: 10.0023x; 10.0023x over previous
//
#include <hip/hip_runtime.h>

// OverlapLoss_intra: B=64, S=256. Odd-sliced boxes, per-batch last-occurrence
// of each id in [0,128), pair all distinct present ids sharing a parent
// (parent taken at the id's last occurrence), sum IoU (inter / min-area).
//
// Structure: kernel A = 64 blocks (one per batch) x 128 threads, writes one
// partial per block to d_ws[b] (unconditional store -> no init/memset needed).
// Kernel B = single wave, reduces the 64 partials into d_out[0].
// Phase-3 scan is vectorized: boxes as float4 in LDS (ds_read_b128), parents
// scanned 8-at-a-time via broadcast int4 reads, fully unrolled.

#define S_DIM 256
#define HALF  128

__global__ __launch_bounds__(128)
void overlap_partial_kernel(const float* __restrict__ pred_boxes,
                            const int* __restrict__ idv_arr,
                            const int* __restrict__ parent_arr,
                            float* __restrict__ partials) {
    const int b = blockIdx.x;
    const int g = threadIdx.x;        // 0..127 : candidate id within batch

    __shared__ int    s_last[HALF];
    __shared__ int    s_par[HALF] __attribute__((aligned(16)));
    __shared__ float4 s_box[HALF];

    s_last[g] = -1;
    __syncthreads();

    // Phase 1: last occurrence of each id among odd slots of row b.
    {
        int idv = idv_arr[b * S_DIM + 2 * g + 1];
        if (idv >= 0 && idv < HALF) atomicMax(&s_last[idv], g);
    }
    __syncthreads();

    // Phase 2: per unique id g, load parent + box at its last occurrence,
    // convert xcycwh (normalized) -> xyxy (pixels).
    int lg = s_last[g];
    int p = -1;
    float4 mybox = make_float4(0.f, 0.f, 0.f, 0.f);
    if (lg >= 0) {
        int flat = b * S_DIM + 2 * lg + 1;
        p = parent_arr[flat];
        float4 bx = reinterpret_cast<const float4*>(pred_boxes)[flat];
        float xc = bx.x * 1440.0f;
        float yc = bx.y * 2560.0f;
        float w  = bx.z * 1440.0f;
        float h  = bx.w * 2560.0f;
        mybox = make_float4(xc - 0.5f * w, yc - 0.5f * h,
                            xc + 0.5f * w, yc + 0.5f * h);
        s_box[g] = mybox;
    }
    s_par[g] = p;
    __syncthreads();

    // Phase 3: pair id g with every id g2 > g sharing the same parent.
    // Parents scanned 8-at-a-time via two broadcast int4 LDS reads.
    float sum = 0.0f;
    if (p >= 0) {
        const float a1 = (mybox.z - mybox.x) * (mybox.w - mybox.y);
        for (int base = 0; base < HALF; base += 8) {
            int4 pa = *reinterpret_cast<const int4*>(&s_par[base]);
            int4 pb = *reinterpret_cast<const int4*>(&s_par[base + 4]);
            const int pars[8] = {pa.x, pa.y, pa.z, pa.w,
                                 pb.x, pb.y, pb.z, pb.w};
            #pragma unroll
            for (int j = 0; j < 8; ++j) {
                const int g2 = base + j;
                if (g2 > g && pars[j] == p) {
                    float4 o = s_box[g2];      // ds_read_b128
                    float xl = fmaxf(mybox.x, o.x);
                    float yt = fmaxf(mybox.y, o.y);
                    float xr = fminf(mybox.z, o.z);
                    float yb = fminf(mybox.w, o.w);
                    if (xr >= xl && yb >= yt) {
                        float a2 = (o.z - o.x) * (o.w - o.y);
                        sum += (xr - xl) * (yb - yt) / fminf(a1, a2);
                    }
                }
            }
        }
    }

    // Block reduction: 2 waves of 64.
    for (int off = 32; off > 0; off >>= 1)
        sum += __shfl_down(sum, off, 64);
    __shared__ float wsum[2];
    if ((g & 63) == 0) wsum[g >> 6] = sum;
    __syncthreads();
    if (g == 0) partials[b] = wsum[0] + wsum[1];
}

__global__ __launch_bounds__(64)
void overlap_reduce_kernel(const float* __restrict__ partials,
                           float* __restrict__ out) {
    float v = partials[threadIdx.x];
    for (int off = 32; off > 0; off >>= 1)
        v += __shfl_down(v, off, 64);
    if (threadIdx.x == 0) out[0] = v;
}

extern "C" void kernel_launch(void* const* d_in, const int* in_sizes, int n_in,
                              void* d_out, int out_size, void* d_ws, size_t ws_size,
                              hipStream_t stream) {
    const float* pred_boxes = (const float*)d_in[0];  // [64,256,4] f32
    const int*   id_        = (const int*)d_in[1];    // [64,256] i32
    const int*   parent_id  = (const int*)d_in[2];    // [64,256] i32
    // d_in[3] = type_id, unused by the reference computation.

    float* partials = (float*)d_ws;   // 64 floats, fully overwritten each call

    overlap_partial_kernel<<<64, 128, 0, stream>>>(pred_boxes, id_, parent_id,
                                                   partials);
    overlap_reduce_kernel<<<1, 64, 0, stream>>>(partials, (float*)d_out);
}